// Round 4
// baseline (825.465 us; speedup 1.0000x reference)
//
#include <hip/hip_runtime.h>

#define D_   32
#define H_   256
#define W_   256
#define HW_  (H_ * W_)
#define DHW_ (D_ * H_ * W_)   // 2097152
#define V_   40000
#define CIN  16
#define COUT 32
#define P_   32
#define EPS_ 1e-5f

#define TD 2
#define TH 8
#define TW 32
#define NTX (W_ / TW)          // 8
#define NTY (H_ / TH)          // 32
#define NTZ (D_ / TD)          // 16
#define NT  (NTX * NTY * NTZ)  // 4096 tiles
#define TPOS (TD * TH * TW)    // 512
#define OH 16                  // channels per block-half

// ---------- K1: feats[v][c] = mean over P ----------
__global__ void feats_kernel(const float* __restrict__ vox, float* __restrict__ feats) {
    int idx = blockIdx.x * 256 + threadIdx.x;      // one thread per (v,c)
    if (idx >= V_ * CIN) return;
    const float4* p = (const float4*)(vox + (size_t)idx * P_);
    float s = 0.f;
#pragma unroll
    for (int j = 0; j < P_ / 4; ++j) {
        float4 q = p[j];
        s += q.x + q.y + q.z + q.w;
    }
    feats[idx] = s * (1.0f / (float)P_);
}

// ---------- K2: per-voxel tap counting into per-tile counters ----------
__global__ void tap_count_kernel(const int* __restrict__ idxs, int* __restrict__ counts) {
    int v = blockIdx.x * 256 + threadIdx.x;
    if (v >= V_) return;
    int w = idxs[3 * v], h = idxs[3 * v + 1], d = idxs[3 * v + 2];
    if (!((unsigned)w < W_ && (unsigned)h < H_ && (unsigned)d < D_)) return;
    int dlo = max(d - 1, 0), dhi = min(d + 1, D_ - 1);
    int hlo = max(h - 1, 0), hhi = min(h + 1, H_ - 1);
    int wlo = max(w - 1, 0), whi = min(w + 1, W_ - 1);
    for (int tz = dlo / TD; tz <= dhi / TD; ++tz) {
        int nd = min(dhi, tz * TD + TD - 1) - max(dlo, tz * TD) + 1;
        for (int ty = hlo / TH; ty <= hhi / TH; ++ty) {
            int nh = min(hhi, ty * TH + TH - 1) - max(hlo, ty * TH) + 1;
            for (int tx = wlo / TW; tx <= whi / TW; ++tx) {
                int nw = min(whi, tx * TW + TW - 1) - max(wlo, tx * TW) + 1;
                atomicAdd(&counts[(tz * NTY + ty) * NTX + tx], nd * nh * nw);
            }
        }
    }
}

// ---------- K3: prefix over 4096 bins + weight transpose ----------
// wt4[((half*27+k)*4+jj)*16+oo] = {conv_w[o][4jj+i][k]}, o = half*16+oo
__global__ void scan_kernel(const int* __restrict__ counts, int* __restrict__ starts,
                            int* __restrict__ cursor, const float* __restrict__ conv_w,
                            float4* __restrict__ wt4) {
    __shared__ int part[256];
    int t = threadIdx.x;
    int base = t * 16;
    int s = 0;
    for (int j = 0; j < 16; ++j) s += counts[base + j];
    part[t] = s;
    __syncthreads();
    for (int off = 1; off < 256; off <<= 1) {
        int val = part[t];
        int add = (t >= off) ? part[t - off] : 0;
        __syncthreads();
        part[t] = val + add;
        __syncthreads();
    }
    int run = (t > 0) ? part[t - 1] : 0;
    for (int j = 0; j < 16; ++j) {
        starts[base + j] = run;
        cursor[base + j] = run;
        run += counts[base + j];
    }
    for (int n = t; n < 2 * 27 * 4 * 16; n += 256) {
        int oo = n & 15;
        int jj = (n >> 4) & 3;
        int m  = n >> 6;
        int k  = m % 27;
        int half = m / 27;
        int o = half * 16 + oo;
        float4 wv;
        wv.x = conv_w[(o * CIN + 4 * jj + 0) * 27 + k];
        wv.y = conv_w[(o * CIN + 4 * jj + 1) * 27 + k];
        wv.z = conv_w[(o * CIN + 4 * jj + 2) * 27 + k];
        wv.w = conv_w[(o * CIN + 4 * jj + 3) * 27 + k];
        wt4[n] = wv;
    }
}

// ---------- K4: per-voxel tap fill (reserve runs, write tile-grouped taps) ----------
__global__ void tap_fill_kernel(const int* __restrict__ idxs, int* __restrict__ cursor,
                                int* __restrict__ taps_g) {
    int v = blockIdx.x * 256 + threadIdx.x;
    if (v >= V_) return;
    int w = idxs[3 * v], h = idxs[3 * v + 1], d = idxs[3 * v + 2];
    if (!((unsigned)w < W_ && (unsigned)h < H_ && (unsigned)d < D_)) return;
    int dlo = max(d - 1, 0), dhi = min(d + 1, D_ - 1);
    int hlo = max(h - 1, 0), hhi = min(h + 1, H_ - 1);
    int wlo = max(w - 1, 0), whi = min(w + 1, W_ - 1);
    for (int tz = dlo / TD; tz <= dhi / TD; ++tz) {
        int sdlo = max(dlo, tz * TD), sdhi = min(dhi, tz * TD + TD - 1);
        for (int ty = hlo / TH; ty <= hhi / TH; ++ty) {
            int shlo = max(hlo, ty * TH), shhi = min(hhi, ty * TH + TH - 1);
            for (int tx = wlo / TW; tx <= whi / TW; ++tx) {
                int swlo = max(wlo, tx * TW), swhi = min(whi, tx * TW + TW - 1);
                int cnt = (sdhi - sdlo + 1) * (shhi - shlo + 1) * (swhi - swlo + 1);
                int p = atomicAdd(&cursor[(tz * NTY + ty) * NTX + tx], cnt);
                for (int dq = sdlo; dq <= sdhi; ++dq)
                    for (int hq = shlo; hq <= shhi; ++hq)
                        for (int wq = swlo; wq <= swhi; ++wq) {
                            int k = ((d - dq + 1) * 3 + (h - hq + 1)) * 3 + (w - wq + 1);
                            int pos = ((dq - tz * TD) * TH + (hq - ty * TH)) * TW +
                                      (wq - tx * TW);
                            taps_g[p++] = (v << 14) | (k << 9) | pos;
                        }
            }
        }
    }
}

// ---------- K5: tile conv. PASS=1: stats only. PASS=2: fused norm+ReLU write ----------
// block = 512 = 16 channels x 32 slots; grid = (NT, 2 halves)
template <int PASS>
__global__ void __launch_bounds__(512, 4) tile_conv_kernel(
    const float4* __restrict__ feats4, const float4* __restrict__ wt4,
    const int* __restrict__ starts, const int* __restrict__ counts,
    const int* __restrict__ taps_g, float* __restrict__ stats,
    const float* __restrict__ mi, float* __restrict__ out)
{
    __shared__ float  tile[TPOS * 16];     // [pos][oo^(pos&15)] xor-swizzled, 32 KB
    __shared__ float4 wsm4[27 * 4 * 16];   // 27 KB
    __shared__ float  wsum[8][16], wsq[8][16];

    int t = threadIdx.x;
    int tile_id = blockIdx.x;
    int half = blockIdx.y;
    int tx = tile_id % NTX, ty = (tile_id / NTX) % NTY, tz = tile_id / (NTX * NTY);
    int w0 = tx * TW, h0 = ty * TH, d0 = tz * TD;
    int obase = half * OH;

    for (int j = t; j < TPOS * 16 / 4; j += 512) ((float4*)tile)[j] = make_float4(0, 0, 0, 0);
    for (int j = t; j < 27 * 4 * 16; j += 512) wsm4[j] = wt4[half * (27 * 4 * 16) + j];
    __syncthreads();

    int base = starts[tile_id];
    int cnt  = counts[tile_id];
    int oo   = t & 15;
    int slot = t >> 4;          // 0..31

    // uniform tap scatter, no barriers inside: streams taps from L2, pipelinable
    for (int j = slot; j < cnt; j += 32) {
        unsigned tap = (unsigned)taps_g[base + j];
        int pos = tap & 511;
        int k = (tap >> 9) & 31;
        int src = tap >> 14;
        const float4* fp = feats4 + src * 4;      // 16-lane broadcast
        float4 f0 = fp[0], f1 = fp[1], f2 = fp[2], f3 = fp[3];
        const float4* wp = &wsm4[(k * 4) * 16 + oo];
        float4 q0 = wp[0], q1 = wp[16], q2 = wp[32], q3 = wp[48];
        float acc = q0.x * f0.x + q0.y * f0.y + q0.z * f0.z + q0.w * f0.w
                  + q1.x * f1.x + q1.y * f1.y + q1.z * f1.z + q1.w * f1.w
                  + q2.x * f2.x + q2.y * f2.y + q2.z * f2.z + q2.w * f2.w
                  + q3.x * f3.x + q3.y * f3.y + q3.z * f3.z + q3.w * f3.w;
        atomicAdd(&tile[pos * 16 + (oo ^ (pos & 15))], acc);
    }
    __syncthreads();

    if (PASS == 1) {
        float s1 = 0.f, s2 = 0.f;
        for (int p = slot; p < TPOS; p += 32) {
            float sv = tile[p * 16 + (oo ^ (p & 15))];
            s1 += sv;
            s2 += sv * sv;
        }
        s1 += __shfl_xor(s1, 16); s2 += __shfl_xor(s2, 16);
        s1 += __shfl_xor(s1, 32); s2 += __shfl_xor(s2, 32);
        int wave = t >> 6, lane = t & 63;
        if (lane < 16) { wsum[wave][lane] = s1; wsq[wave][lane] = s2; }
        __syncthreads();
        if (t < 16) {
            float a = 0.f, b = 0.f;
#pragma unroll
            for (int wv = 0; wv < 8; ++wv) { a += wsum[wv][t]; b += wsq[wv][t]; }
            atomicAdd(&stats[obase + t], a);
            atomicAdd(&stats[COUT + obase + t], b);
        }
    } else {
        // y = relu(s*A + B), single coalesced write of the final output
        int wl = t & 31;
        for (int r = t >> 5; r < OH * TD * TH; r += 16) {
            int oo2 = r >> 4;          // TD*TH = 16
            int rem = r & 15;
            int o = obase + oo2;
            float A = mi[o], B = mi[COUT + o];
            int pos = rem * TW + wl;
            float s = tile[pos * 16 + (oo2 ^ (pos & 15))];
            int dl = rem >> 3, hl = rem & 7;
            out[(size_t)o * DHW_ + (size_t)(d0 + dl) * HW_ + (size_t)(h0 + hl) * W_ +
                (w0 + wl)] = fmaxf(s * A + B, 0.f);
        }
    }
}

// ---------- K6: finalize per-channel scale A and shift B ----------
// x = bias + s; mean = bias + m1; var = m2 - m1^2 (bias cancels analytically)
__global__ void finalize_kernel(const float* __restrict__ stats,
                                const float* __restrict__ gamma,
                                const float* __restrict__ beta,
                                float* __restrict__ mi) {
    int t = threadIdx.x;
    if (t < COUT) {
        float n = (float)DHW_;
        float m1 = stats[t] / n;
        float m2 = stats[COUT + t] / n;
        float var = fmaxf(m2 - m1 * m1, 0.f);
        float inv = rsqrtf(var + EPS_);
        float A = gamma[t] * inv;
        mi[t] = A;
        mi[COUT + t] = -m1 * A + beta[t];
    }
}

extern "C" void kernel_launch(void* const* d_in, const int* in_sizes, int n_in,
                              void* d_out, int out_size, void* d_ws, size_t ws_size,
                              hipStream_t stream) {
    const float* voxels  = (const float*)d_in[0];
    const int*   indices = (const int*)  d_in[1];
    const float* conv_w  = (const float*)d_in[2];
    const float* gamma   = (const float*)d_in[4];
    const float* beta    = (const float*)d_in[5];
    float* out = (float*)d_out;

    float4* wt4    = (float4*)d_ws;                      // 3456 float4
    float*  feats  = (float*)(wt4 + 3456);               // V*CIN floats
    int*    counts = (int*)(feats + (size_t)V_ * CIN);   // NT
    int*    starts = counts + NT;
    int*    cursor = starts + NT;
    int*    taps_g = cursor + NT;                        // <= V*27 = 1.08M ints
    float*  stats  = (float*)(taps_g + (size_t)V_ * 27); // 64
    float*  mi     = stats + 2 * COUT;                   // 64

    hipMemsetAsync(counts, 0, NT * sizeof(int), stream);
    hipMemsetAsync(stats, 0, 2 * COUT * sizeof(float), stream);

    feats_kernel<<<(V_ * CIN + 255) / 256, 256, 0, stream>>>(voxels, feats);
    tap_count_kernel<<<(V_ + 255) / 256, 256, 0, stream>>>(indices, counts);
    scan_kernel<<<1, 256, 0, stream>>>(counts, starts, cursor, conv_w, wt4);
    tap_fill_kernel<<<(V_ + 255) / 256, 256, 0, stream>>>(indices, cursor, taps_g);

    dim3 grid(NT, 2);
    tile_conv_kernel<1><<<grid, 512, 0, stream>>>((const float4*)feats, wt4, starts,
                                                  counts, taps_g, stats, mi, out);
    finalize_kernel<<<1, 64, 0, stream>>>(stats, gamma, beta, mi);
    tile_conv_kernel<2><<<grid, 512, 0, stream>>>((const float4*)feats, wt4, starts,
                                                  counts, taps_g, stats, mi, out);
}

// Round 5
// 809.682 us; speedup vs baseline: 1.0195x; 1.0195x over previous
//
#include <hip/hip_runtime.h>

#define D_   32
#define H_   256
#define W_   256
#define HW_  (H_ * W_)
#define DHW_ (D_ * H_ * W_)   // 2097152
#define V_   40000
#define CIN  16
#define COUT 32
#define P_   32
#define EPS_ 1e-5f

#define TD 2
#define TH 8
#define TW 32
#define NTX (W_ / TW)          // 8
#define NTY (H_ / TH)          // 32
#define NTZ (D_ / TD)          // 16
#define NT  (NTX * NTY * NTX * 0 + NTX * NTY * NTZ)  // 4096 tiles
#define TPOS (TD * TH * TW)    // 512
#define OH 16                  // channels per block-half

#define FEATS_BLOCKS ((V_ * CIN + 255) / 256)   // 2500
#define COUNT_BLOCKS ((V_ + 255) / 256)         // 157

// ---------- K1 merged: feats mean + per-tile tap counting ----------
__global__ void prep_kernel(const float* __restrict__ vox, const int* __restrict__ idxs,
                            float* __restrict__ feats, int* __restrict__ counts) {
    int blk = blockIdx.x;
    if (blk < FEATS_BLOCKS) {
        int idx = blk * 256 + threadIdx.x;      // one thread per (v,c)
        if (idx >= V_ * CIN) return;
        const float4* p = (const float4*)(vox + (size_t)idx * P_);
        float s = 0.f;
#pragma unroll
        for (int j = 0; j < P_ / 4; ++j) {
            float4 q = p[j];
            s += q.x + q.y + q.z + q.w;
        }
        feats[idx] = s * (1.0f / (float)P_);
    } else {
        int v = (blk - FEATS_BLOCKS) * 256 + threadIdx.x;
        if (v >= V_) return;
        int w = idxs[3 * v], h = idxs[3 * v + 1], d = idxs[3 * v + 2];
        if (!((unsigned)w < W_ && (unsigned)h < H_ && (unsigned)d < D_)) return;
        int dlo = max(d - 1, 0), dhi = min(d + 1, D_ - 1);
        int hlo = max(h - 1, 0), hhi = min(h + 1, H_ - 1);
        int wlo = max(w - 1, 0), whi = min(w + 1, W_ - 1);
        for (int tz = dlo / TD; tz <= dhi / TD; ++tz) {
            int nd = min(dhi, tz * TD + TD - 1) - max(dlo, tz * TD) + 1;
            for (int ty = hlo / TH; ty <= hhi / TH; ++ty) {
                int nh = min(hhi, ty * TH + TH - 1) - max(hlo, ty * TH) + 1;
                for (int tx = wlo / TW; tx <= whi / TW; ++tx) {
                    int nw = min(whi, tx * TW + TW - 1) - max(wlo, tx * TW) + 1;
                    atomicAdd(&counts[(tz * NTY + ty) * NTX + tx], nd * nh * nw);
                }
            }
        }
    }
}

// ---------- K2: prefix over 4096 bins (4-aligned starts) + wt transpose + zero stats --
// wt4[((half*27+k)*4+jj)*16+oo] = {conv_w[o][4jj+i][k]}, o = half*16+oo
__global__ void scan_kernel(const int* __restrict__ counts, int* __restrict__ starts,
                            int* __restrict__ cursor, const float* __restrict__ conv_w,
                            float4* __restrict__ wt4, float* __restrict__ stats) {
    __shared__ int part[256];
    int t = threadIdx.x;
    int pc[16];
    {
        const int4* c4 = (const int4*)counts + t * 4;
        int4 a = c4[0], b = c4[1], c = c4[2], d = c4[3];
        pc[0] = a.x; pc[1] = a.y; pc[2] = a.z; pc[3] = a.w;
        pc[4] = b.x; pc[5] = b.y; pc[6] = b.z; pc[7] = b.w;
        pc[8] = c.x; pc[9] = c.y; pc[10] = c.z; pc[11] = c.w;
        pc[12] = d.x; pc[13] = d.y; pc[14] = d.z; pc[15] = d.w;
    }
    int s = 0;
#pragma unroll
    for (int j = 0; j < 16; ++j) { pc[j] = (pc[j] + 3) & ~3; s += pc[j]; }
    part[t] = s;
    __syncthreads();
    for (int off = 1; off < 256; off <<= 1) {
        int val = part[t];
        int add = (t >= off) ? part[t - off] : 0;
        __syncthreads();
        part[t] = val + add;
        __syncthreads();
    }
    int run = (t > 0) ? part[t - 1] : 0;
    int base = t * 16;
#pragma unroll
    for (int j = 0; j < 16; ++j) {
        starts[base + j] = run;
        cursor[base + j] = run;
        run += pc[j];
    }
    if (t < 2 * COUT) stats[t] = 0.f;
    for (int n = t; n < 2 * 27 * 4 * 16; n += 256) {
        int oo = n & 15;
        int jj = (n >> 4) & 3;
        int m  = n >> 6;
        int k  = m % 27;
        int half = m / 27;
        int o = half * 16 + oo;
        float4 wv;
        wv.x = conv_w[(o * CIN + 4 * jj + 0) * 27 + k];
        wv.y = conv_w[(o * CIN + 4 * jj + 1) * 27 + k];
        wv.z = conv_w[(o * CIN + 4 * jj + 2) * 27 + k];
        wv.w = conv_w[(o * CIN + 4 * jj + 3) * 27 + k];
        wt4[n] = wv;
    }
}

// ---------- K3: per-voxel tap fill (reserve runs, write tile-grouped taps) ----------
__global__ void tap_fill_kernel(const int* __restrict__ idxs, int* __restrict__ cursor,
                                int* __restrict__ taps_g) {
    int v = blockIdx.x * 256 + threadIdx.x;
    if (v >= V_) return;
    int w = idxs[3 * v], h = idxs[3 * v + 1], d = idxs[3 * v + 2];
    if (!((unsigned)w < W_ && (unsigned)h < H_ && (unsigned)d < D_)) return;
    int dlo = max(d - 1, 0), dhi = min(d + 1, D_ - 1);
    int hlo = max(h - 1, 0), hhi = min(h + 1, H_ - 1);
    int wlo = max(w - 1, 0), whi = min(w + 1, W_ - 1);
    for (int tz = dlo / TD; tz <= dhi / TD; ++tz) {
        int sdlo = max(dlo, tz * TD), sdhi = min(dhi, tz * TD + TD - 1);
        for (int ty = hlo / TH; ty <= hhi / TH; ++ty) {
            int shlo = max(hlo, ty * TH), shhi = min(hhi, ty * TH + TH - 1);
            for (int tx = wlo / TW; tx <= whi / TW; ++tx) {
                int swlo = max(wlo, tx * TW), swhi = min(whi, tx * TW + TW - 1);
                int cnt = (sdhi - sdlo + 1) * (shhi - shlo + 1) * (swhi - swlo + 1);
                int p = atomicAdd(&cursor[(tz * NTY + ty) * NTX + tx], cnt);
                for (int dq = sdlo; dq <= sdhi; ++dq)
                    for (int hq = shlo; hq <= shhi; ++hq)
                        for (int wq = swlo; wq <= swhi; ++wq) {
                            int k = ((d - dq + 1) * 3 + (h - hq + 1)) * 3 + (w - wq + 1);
                            int pos = ((dq - tz * TD) * TH + (hq - ty * TH)) * TW +
                                      (wq - tx * TW);
                            taps_g[p++] = (v << 14) | (k << 9) | pos;
                        }
            }
        }
    }
}

__device__ __forceinline__ float dot16(float4 a0, float4 a1, float4 a2, float4 a3,
                                       float4 b0, float4 b1, float4 b2, float4 b3) {
    return a0.x * b0.x + a0.y * b0.y + a0.z * b0.z + a0.w * b0.w
         + a1.x * b1.x + a1.y * b1.y + a1.z * b1.z + a1.w * b1.w
         + a2.x * b2.x + a2.y * b2.y + a2.z * b2.z + a2.w * b2.w
         + a3.x * b3.x + a3.y * b3.y + a3.z * b3.z + a3.w * b3.w;
}

// ---------- K4/K5: tile conv. PASS=1: stats only. PASS=2: fused norm+ReLU write ------
// block = 512 = 16 channels x 32 slots; grid = (NT, 2 halves)
template <int PASS>
__global__ void __launch_bounds__(512, 4) tile_conv_kernel(
    const float4* __restrict__ feats4, const float4* __restrict__ wt4,
    const int* __restrict__ starts, const int* __restrict__ counts,
    const int* __restrict__ taps_g, float* __restrict__ stats,
    const float* __restrict__ gamma, const float* __restrict__ beta,
    float* __restrict__ out)
{
    __shared__ float  tile[TPOS * 16];     // [pos][oo^(pos&15)] xor-swizzled, 32 KB
    __shared__ float4 wsm4[27 * 4 * 16];   // 27 KB
    __shared__ float  wsum[8][16], wsq[8][16];
    __shared__ float  AB[2][16];

    int t = threadIdx.x;
    int tile_id = blockIdx.x;
    int half = blockIdx.y;
    int tx = tile_id % NTX, ty = (tile_id / NTX) % NTY, tz = tile_id / (NTX * NTY);
    int w0 = tx * TW, h0 = ty * TH, d0 = tz * TD;
    int obase = half * OH;

    for (int j = t; j < TPOS * 16 / 4; j += 512) ((float4*)tile)[j] = make_float4(0, 0, 0, 0);
    for (int j = t; j < 27 * 4 * 16; j += 512) wsm4[j] = wt4[half * (27 * 4 * 16) + j];
    if (PASS == 2 && t < 16) {
        // inline finalize: x = bias + s; mean = bias + m1; var = m2 - m1^2 (bias cancels)
        int o = obase + t;
        float n = (float)DHW_;
        float m1 = stats[o] / n;
        float m2 = stats[COUT + o] / n;
        float var = fmaxf(m2 - m1 * m1, 0.f);
        float inv = rsqrtf(var + EPS_);
        float A = gamma[o] * inv;
        AB[0][t] = A;
        AB[1][t] = -m1 * A + beta[o];
    }
    __syncthreads();

    int base = starts[tile_id];   // 4-aligned
    int cnt  = counts[tile_id];
    int oo   = t & 15;
    int slot = t >> 4;            // 0..31

    // uniform tap scatter, 2-wide unrolled: both taps' loads issued before either dot
    const int2* tg2 = (const int2*)(taps_g + base);
    int cnt2 = (cnt + 1) >> 1;
    for (int g = slot; g < cnt2; g += 32) {
        int2 tw = tg2[g];
        unsigned u0 = (unsigned)tw.x, u1 = (unsigned)tw.y;
        bool pairok = (2 * g + 1) < cnt;
        if (!pairok) u1 = u0;
        int p0 = u0 & 511, k0 = (u0 >> 9) & 31; unsigned s0 = u0 >> 14;
        int p1 = u1 & 511, k1 = (u1 >> 9) & 31; unsigned s1 = u1 >> 14;
        const float4* fA = feats4 + s0 * 4;
        const float4* fB = feats4 + s1 * 4;
        float4 a0 = fA[0], a1 = fA[1], a2 = fA[2], a3 = fA[3];
        float4 b0 = fB[0], b1 = fB[1], b2 = fB[2], b3 = fB[3];
        const float4* wA = &wsm4[k0 * 64 + oo];
        const float4* wB = &wsm4[k1 * 64 + oo];
        float4 qa0 = wA[0], qa1 = wA[16], qa2 = wA[32], qa3 = wA[48];
        float4 qb0 = wB[0], qb1 = wB[16], qb2 = wB[32], qb3 = wB[48];
        float acc0 = dot16(a0, a1, a2, a3, qa0, qa1, qa2, qa3);
        float acc1 = dot16(b0, b1, b2, b3, qb0, qb1, qb2, qb3);
        atomicAdd(&tile[p0 * 16 + (oo ^ (p0 & 15))], acc0);
        if (pairok) atomicAdd(&tile[p1 * 16 + (oo ^ (p1 & 15))], acc1);
    }
    __syncthreads();

    if (PASS == 1) {
        float s1 = 0.f, s2 = 0.f;
        for (int p = slot; p < TPOS; p += 32) {
            float sv = tile[p * 16 + (oo ^ (p & 15))];
            s1 += sv;
            s2 += sv * sv;
        }
        s1 += __shfl_xor(s1, 16); s2 += __shfl_xor(s2, 16);
        s1 += __shfl_xor(s1, 32); s2 += __shfl_xor(s2, 32);
        int wave = t >> 6, lane = t & 63;
        if (lane < 16) { wsum[wave][lane] = s1; wsq[wave][lane] = s2; }
        __syncthreads();
        if (t < 16) {
            float a = 0.f, b = 0.f;
#pragma unroll
            for (int wv = 0; wv < 8; ++wv) { a += wsum[wv][t]; b += wsq[wv][t]; }
            atomicAdd(&stats[obase + t], a);
            atomicAdd(&stats[COUT + obase + t], b);
        }
    } else {
        // y = relu(s*A + B), single coalesced write of the final output
        int wl = t & 31;
        for (int r = t >> 5; r < OH * TD * TH; r += 16) {
            int oo2 = r >> 4;          // TD*TH = 16
            int rem = r & 15;
            float A = AB[0][oo2], B = AB[1][oo2];
            int pos = rem * TW + wl;
            float s = tile[pos * 16 + (oo2 ^ (pos & 15))];
            int dl = rem >> 3, hl = rem & 7;
            out[(size_t)(obase + oo2) * DHW_ + (size_t)(d0 + dl) * HW_ +
                (size_t)(h0 + hl) * W_ + (w0 + wl)] = fmaxf(s * A + B, 0.f);
        }
    }
}

extern "C" void kernel_launch(void* const* d_in, const int* in_sizes, int n_in,
                              void* d_out, int out_size, void* d_ws, size_t ws_size,
                              hipStream_t stream) {
    const float* voxels  = (const float*)d_in[0];
    const int*   indices = (const int*)  d_in[1];
    const float* conv_w  = (const float*)d_in[2];
    const float* gamma   = (const float*)d_in[4];
    const float* beta    = (const float*)d_in[5];
    float* out = (float*)d_out;

    float4* wt4    = (float4*)d_ws;                      // 3456 float4
    float*  feats  = (float*)(wt4 + 3456);               // V*CIN floats
    int*    counts = (int*)(feats + (size_t)V_ * CIN);   // NT
    int*    starts = counts + NT;
    int*    cursor = starts + NT;
    int*    taps_g = cursor + NT;                        // <= V*27 + 4*NT ints
    float*  stats  = (float*)(taps_g + (size_t)V_ * 27 + 4 * NT);   // 64

    hipMemsetAsync(counts, 0, NT * sizeof(int), stream);

    prep_kernel<<<FEATS_BLOCKS + COUNT_BLOCKS, 256, 0, stream>>>(voxels, indices,
                                                                 feats, counts);
    scan_kernel<<<1, 256, 0, stream>>>(counts, starts, cursor, conv_w, wt4, stats);
    tap_fill_kernel<<<COUNT_BLOCKS, 256, 0, stream>>>(indices, cursor, taps_g);

    dim3 grid(NT, 2);
    tile_conv_kernel<1><<<grid, 512, 0, stream>>>((const float4*)feats, wt4, starts,
                                                  counts, taps_g, stats, gamma, beta, out);
    tile_conv_kernel<2><<<grid, 512, 0, stream>>>((const float4*)feats, wt4, starts,
                                                  counts, taps_g, stats, gamma, beta, out);
}